// Round 4
// baseline (373.804 us; speedup 1.0000x reference)
//
#include <hip/hip_runtime.h>

// 2-layer GCN, restructured:
//   ag1[n]  = bf16(emb[x_ids[n]] * dinv[n])                 (16bf, 3.2MB: L2-resident)
//   s1[c]   = dinv[c] * (sum_{r->c} ag1[r] + ag1[c])        (16f)  [CSR gather]
//   y1g[n]  = bf16(relu(s1[n] @ W1 + b1) * dinv[n])         (2 planes x 16bf, 3.2MB each)
//   s2[c]   = dinv[c] * (sum_{r->c} y1g[r] + y1g[c])        (per-plane CSR gather)
//   out[g]  = (sum_{batch==g} s2) @ W2 + cnt[g]*b2          (fused pool+GEMV)
//
// R3 lesson: k_agg2 was fetch-volume-bound (164MB: 12.8MB f32 rows miss the
// 4MB per-XCD L2). bf16 + feature-plane split puts each gather pass's working
// set (3.2MB) inside L2. CSR build keeps the R3 partitioned counting sort
// (dense per-block stores, LDS-only atomics).

constexpr int BLK = 256;
constexpr int EPB = 8192;          // edges per block in hist/scatter
constexpr int BSH = 10;            // 1024 nodes per bucket
constexpr int BKTN = 1 << BSH;

__device__ inline unsigned short f2bf(float x) {
  unsigned u = __float_as_uint(x);
  u += 0x7FFF + ((u >> 16) & 1);   // round-to-nearest-even
  return (unsigned short)(u >> 16);
}
__device__ inline float bf2f(unsigned short h) {
  return __uint_as_float((unsigned)h << 16);
}

// per-block LDS histogram of col buckets
__global__ __launch_bounds__(BLK) void k_hist(const int* __restrict__ col, int E,
                                              int nbkt, int nblk,
                                              int* __restrict__ hist) {
  __shared__ int h[1024];
  int tid = threadIdx.x, blk = blockIdx.x;
  for (int i = tid; i < nbkt; i += BLK) h[i] = 0;
  __syncthreads();
  int e0 = blk * EPB, e1 = min(E, e0 + EPB);
  for (int e = e0 + tid; e < e1; e += BLK) atomicAdd(&h[col[e] >> BSH], 1);
  __syncthreads();
  for (int b = tid; b < nbkt; b += BLK) hist[b * nblk + blk] = h[b];
}

// single-block exclusive scan of hist (bucket-major) -> off; bucket starts
__global__ __launch_bounds__(1024) void k_gscan(const int* __restrict__ hist,
                                                int tot, int nblk, int nbkt, int E,
                                                int* __restrict__ off,
                                                int* __restrict__ bucket_off) {
  __shared__ int sd[1024];
  int tid = threadIdx.x;
  int C = (tot + 1023) >> 10;
  int lo = tid * C, hi = min(tot, lo + C);
  int sum = 0;
  for (int i = lo; i < hi; ++i) sum += hist[i];
  sd[tid] = sum;
  __syncthreads();
  for (int o = 1; o < 1024; o <<= 1) {
    int v = (tid >= o) ? sd[tid - o] : 0;
    __syncthreads();
    sd[tid] += v;
    __syncthreads();
  }
  int run = sd[tid] - sum;  // exclusive
  for (int i = lo; i < hi; ++i) {
    off[i] = run;
    if (i % nblk == 0) bucket_off[i / nblk] = run;
    run += hist[i];
  }
  if (tid == 0) bucket_off[nbkt] = E;
}

// scatter packed edges into bucket-major segments; all stores dense per block
__global__ __launch_bounds__(BLK) void k_scatter(const int* __restrict__ row,
                                                 const int* __restrict__ col, int E,
                                                 int nbkt, int nblk,
                                                 const int* __restrict__ off,
                                                 int* __restrict__ staging) {
  __shared__ int base[1024];
  __shared__ int cur[1024];
  int tid = threadIdx.x, blk = blockIdx.x;
  for (int b = tid; b < nbkt; b += BLK) {
    base[b] = off[b * nblk + blk];
    cur[b] = 0;
  }
  __syncthreads();
  int e0 = blk * EPB, e1 = min(E, e0 + EPB);
  for (int e = e0 + tid; e < e1; e += BLK) {
    int c = col[e];
    int b = c >> BSH;
    int rk = atomicAdd(&cur[b], 1);
    staging[base[b] + rk] = (row[e] << BSH) | (c & (BKTN - 1));
  }
}

// per-bucket (1024 nodes): LDS count -> scan -> col_ptr/dinv -> edge_row fill
__global__ __launch_bounds__(1024) void k_build(const int* __restrict__ staging,
                                                const int* __restrict__ bucket_off,
                                                int N, int E,
                                                int* __restrict__ col_ptr,
                                                float* __restrict__ dinv,
                                                int* __restrict__ edge_row) {
  __shared__ int cnt[BKTN];
  __shared__ int sc[BKTN];
  __shared__ int lcur[BKTN];
  int tid = threadIdx.x, b = blockIdx.x;
  int beg = bucket_off[b], end = bucket_off[b + 1];
  cnt[tid] = 0;
  __syncthreads();
  for (int i = beg + tid; i < end; i += 1024)
    atomicAdd(&cnt[staging[i] & (BKTN - 1)], 1);
  __syncthreads();
  int c = cnt[tid];
  sc[tid] = c;
  __syncthreads();
  for (int o = 1; o < BKTN; o <<= 1) {
    int v = (tid >= o) ? sc[tid - o] : 0;
    __syncthreads();
    sc[tid] += v;
    __syncthreads();
  }
  int node = (b << BSH) + tid;
  if (node < N) {
    int pos = beg + sc[tid] - c;
    col_ptr[node] = pos;
    lcur[tid] = pos;
    dinv[node] = rsqrtf((float)(c + 1));  // +1 self-loop
  }
  if (b == 0 && tid == 0) col_ptr[N] = E;
  __syncthreads();
  for (int i = beg + tid; i < end; i += 1024) {
    int p = staging[i];
    int pos = atomicAdd(&lcur[p & (BKTN - 1)], 1);
    edge_row[pos] = p >> BSH;
  }
}

// ag1[n] = bf16(emb[x_ids[n]] * dinv[n]); 2 lanes/node x 8 feats
__global__ __launch_bounds__(BLK) void k_prep(const int* __restrict__ x_ids,
                                              const float* __restrict__ emb,
                                              const float* __restrict__ dinv, int N,
                                              unsigned short* __restrict__ ag1) {
  int t = blockIdx.x * BLK + threadIdx.x;
  int n = t >> 1, half = t & 1;
  if (n >= N) return;
  float d = dinv[n];
  const float* er = emb + (size_t)x_ids[n] * 16 + half * 8;
  float4 a = *(const float4*)(er);
  float4 b = *(const float4*)(er + 4);
  uint4 o;
  o.x = (unsigned)f2bf(a.x * d) | ((unsigned)f2bf(a.y * d) << 16);
  o.y = (unsigned)f2bf(a.z * d) | ((unsigned)f2bf(a.w * d) << 16);
  o.z = (unsigned)f2bf(b.x * d) | ((unsigned)f2bf(b.y * d) << 16);
  o.w = (unsigned)f2bf(b.z * d) | ((unsigned)f2bf(b.w * d) << 16);
  *(uint4*)(ag1 + (size_t)n * 16 + half * 8) = o;
}

// s1[c] = dinv[c] * (sum ag1[r] + ag1[c]); 4 lanes/node x 4 feats (bf16 in)
__global__ __launch_bounds__(BLK) void k_agg1(const unsigned short* __restrict__ ag1,
                                              const int* __restrict__ col_ptr,
                                              const int* __restrict__ edge_row,
                                              const float* __restrict__ dinv, int N,
                                              float* __restrict__ s1) {
  int t = blockIdx.x * BLK + threadIdx.x;
  int n = t >> 2, ch = t & 3;
  if (n >= N) return;
  int off = ch * 4;
  uint2 sv = *(const uint2*)(ag1 + (size_t)n * 16 + off);
  float a0 = bf2f(sv.x & 0xFFFF), a1 = bf2f(sv.x >> 16);
  float a2 = bf2f(sv.y & 0xFFFF), a3 = bf2f(sv.y >> 16);
  int beg = col_ptr[n], end = col_ptr[n + 1];
  for (int i = beg; i < end; ++i) {
    int r = edge_row[i];
    uint2 v = *(const uint2*)(ag1 + (size_t)r * 16 + off);
    a0 += bf2f(v.x & 0xFFFF); a1 += bf2f(v.x >> 16);
    a2 += bf2f(v.y & 0xFFFF); a3 += bf2f(v.y >> 16);
  }
  float d = dinv[n];
  float4 o = {a0 * d, a1 * d, a2 * d, a3 * d};
  *(float4*)(s1 + (size_t)n * 16 + off) = o;
}

// y1g[n] = bf16(relu(s1[n] @ W1 + b1) * dinv[n]); written as 2 planes x 16bf
__global__ __launch_bounds__(BLK) void k_t1(const float* __restrict__ s1,
                                            const float* __restrict__ W1,
                                            const float* __restrict__ b1,
                                            const float* __restrict__ dinv, int N,
                                            unsigned short* __restrict__ y1g) {
  __shared__ float W[16 * 32];
  __shared__ float bb[32];
  int tid = threadIdx.x;
  for (int i = tid; i < 512; i += BLK) W[i] = W1[i];
  if (tid < 32) bb[tid] = b1[tid];
  __syncthreads();
  int t = blockIdx.x * BLK + tid;
  int n = t >> 3, ch = t & 7;
  if (n >= N) return;
  const float* sr = s1 + (size_t)n * 16;
  float x[16];
#pragma unroll
  for (int k = 0; k < 16; ++k) x[k] = sr[k];
  int f0 = ch * 4;
  float a0 = bb[f0], a1 = bb[f0 + 1], a2 = bb[f0 + 2], a3 = bb[f0 + 3];
#pragma unroll
  for (int k = 0; k < 16; ++k) {
    float xv = x[k];
    const float* wr = &W[k * 32 + f0];
    a0 += xv * wr[0]; a1 += xv * wr[1]; a2 += xv * wr[2]; a3 += xv * wr[3];
  }
  float d = dinv[n];
  a0 = fmaxf(a0, 0.f) * d;
  a1 = fmaxf(a1, 0.f) * d;
  a2 = fmaxf(a2, 0.f) * d;
  a3 = fmaxf(a3, 0.f) * d;
  int plane = ch >> 2, col0 = f0 & 15;
  uint2 o;
  o.x = (unsigned)f2bf(a0) | ((unsigned)f2bf(a1) << 16);
  o.y = (unsigned)f2bf(a2) | ((unsigned)f2bf(a3) << 16);
  *(uint2*)(y1g + (size_t)plane * N * 16 + (size_t)n * 16 + col0) = o;
}

// per-plane: s2p[c] = dinv[c]*(sum y1p[r] + y1p[c]); 4 lanes/node x 4 feats
__global__ __launch_bounds__(BLK) void k_agg2(const unsigned short* __restrict__ y1p,
                                              const int* __restrict__ col_ptr,
                                              const int* __restrict__ edge_row,
                                              const float* __restrict__ dinv, int N,
                                              float* __restrict__ s2p) {
  int t = blockIdx.x * BLK + threadIdx.x;
  int n = t >> 2, ch = t & 3;
  if (n >= N) return;
  int off = ch * 4;
  uint2 sv = *(const uint2*)(y1p + (size_t)n * 16 + off);
  float a0 = bf2f(sv.x & 0xFFFF), a1 = bf2f(sv.x >> 16);
  float a2 = bf2f(sv.y & 0xFFFF), a3 = bf2f(sv.y >> 16);
  int beg = col_ptr[n], end = col_ptr[n + 1];
  for (int i = beg; i < end; ++i) {
    int r = edge_row[i];
    uint2 v = *(const uint2*)(y1p + (size_t)r * 16 + off);
    a0 += bf2f(v.x & 0xFFFF); a1 += bf2f(v.x >> 16);
    a2 += bf2f(v.y & 0xFFFF); a3 += bf2f(v.y >> 16);
  }
  float d = dinv[n];
  float4 o = {a0 * d, a1 * d, a2 * d, a3 * d};
  *(float4*)(s2p + (size_t)n * 16 + off) = o;
}

// batch is SORTED: block g binary-searches its node range, sums s2 rows
// (plane-major layout), then out[g] = psum @ W2 + cnt*b2. No atomics.
__global__ __launch_bounds__(BLK) void k_pool(const float* __restrict__ s2,
                                              const int* __restrict__ batch, int N,
                                              const float* __restrict__ W2,
                                              const float* __restrict__ b2,
                                              float* __restrict__ out) {
  __shared__ int se[2];
  __shared__ float sd[BLK];
  int g = blockIdx.x, tid = threadIdx.x;
  if (tid < 2) {
    int v = g + tid;
    int lo = 0, hi = N;
    while (lo < hi) {
      int mid = (lo + hi) >> 1;
      if (batch[mid] < v) lo = mid + 1; else hi = mid;
    }
    se[tid] = lo;
  }
  __syncthreads();
  int start = se[0], end = se[1];
  int f = tid & 31, grp = tid >> 5;
  const float* base = s2 + (size_t)(f >> 4) * N * 16 + (f & 15);
  float acc = 0.f;
  for (int n = start + grp; n < end; n += 8) acc += base[(size_t)n * 16];
  sd[tid] = acc;
  __syncthreads();
  if (tid < 128) sd[tid] += sd[tid + 128];
  __syncthreads();
  if (tid < 64) sd[tid] += sd[tid + 64];
  __syncthreads();
  if (tid < 32) sd[tid] += sd[tid + 32];
  __syncthreads();
  if (tid < 41) {
    float o = (float)(end - start) * b2[tid];
#pragma unroll
    for (int k = 0; k < 32; ++k) o += sd[k] * W2[k * 41 + tid];
    out[(size_t)g * 41 + tid] = o;
  }
}

extern "C" void kernel_launch(void* const* d_in, const int* in_sizes, int n_in,
                              void* d_out, int out_size, void* d_ws, size_t ws_size,
                              hipStream_t stream) {
  const int* x_ids = (const int*)d_in[0];
  const int* edge_index = (const int*)d_in[1];
  const int* batch = (const int*)d_in[2];
  const float* emb = (const float*)d_in[3];
  const float* W1 = (const float*)d_in[4];
  const float* b1 = (const float*)d_in[5];
  const float* W2 = (const float*)d_in[6];
  const float* b2 = (const float*)d_in[7];
  float* out = (float*)d_out;

  const int N = in_sizes[0];
  const int E = in_sizes[1] / 2;
  const int G = out_size / 41;
  const int* row = edge_index;
  const int* col = edge_index + E;

  const int nbkt = (N + BKTN - 1) >> BSH;       // 98
  const int nblk = (E + EPB - 1) / EPB;         // 391
  const int tot = nbkt * nblk;

  char* ws = (char*)d_ws;
  size_t woff = 0;
  auto alloc = [&](size_t bytes) -> char* {
    char* p = ws + woff;
    woff += (bytes + 255) & ~(size_t)255;
    return p;
  };
  size_t stage_bytes = (size_t)E * 4;
  size_t s2_bytes = (size_t)N * 32 * 4;
  int* staging = (int*)alloc(stage_bytes > s2_bytes ? stage_bytes : s2_bytes);
  int* edge_row = (int*)alloc((size_t)E * 4);
  int* col_ptr = (int*)alloc(((size_t)N + 1) * 4);
  float* dinv = (float*)alloc((size_t)N * 4);
  unsigned short* ag1 = (unsigned short*)alloc((size_t)N * 16 * 2);
  float* s1 = (float*)alloc((size_t)N * 16 * 4);
  unsigned short* y1g = (unsigned short*)alloc((size_t)N * 32 * 2);
  int* hist = (int*)alloc((size_t)tot * 4);
  int* off = (int*)alloc((size_t)tot * 4);
  int* bucket_off = (int*)alloc(((size_t)nbkt + 1) * 4);
  float* s2 = (float*)staging;  // staging dead after k_build
  (void)ws_size; (void)n_in;

  k_hist<<<nblk, BLK, 0, stream>>>(col, E, nbkt, nblk, hist);
  k_gscan<<<1, 1024, 0, stream>>>(hist, tot, nblk, nbkt, E, off, bucket_off);
  k_scatter<<<nblk, BLK, 0, stream>>>(row, col, E, nbkt, nblk, off, staging);
  k_build<<<nbkt, 1024, 0, stream>>>(staging, bucket_off, N, E, col_ptr, dinv, edge_row);
  k_prep<<<(N * 2 + BLK - 1) / BLK, BLK, 0, stream>>>(x_ids, emb, dinv, N, ag1);
  k_agg1<<<(N * 4 + BLK - 1) / BLK, BLK, 0, stream>>>(ag1, col_ptr, edge_row, dinv, N, s1);
  k_t1<<<(N * 8 + BLK - 1) / BLK, BLK, 0, stream>>>(s1, W1, b1, dinv, N, y1g);
  k_agg2<<<(N * 4 + BLK - 1) / BLK, BLK, 0, stream>>>(y1g, col_ptr, edge_row, dinv, N, s2);
  k_agg2<<<(N * 4 + BLK - 1) / BLK, BLK, 0, stream>>>(y1g + (size_t)N * 16, col_ptr,
                                                      edge_row, dinv, N, s2 + (size_t)N * 16);
  k_pool<<<G, BLK, 0, stream>>>(s2, batch, N, W2, b2, out);
}

// Round 5
// 318.657 us; speedup vs baseline: 1.1731x; 1.1731x over previous
//
#include <hip/hip_runtime.h>

// 2-layer GCN, restructured:
//   ag1[n]  = bf16(emb[x_ids[n]] * dinv[n])                 (16bf, 3.2MB: L2-resident)
//   s1[c]   = dinv[c] * (sum_{r->c} ag1[r] + ag1[c])        (16f)  [CSR gather]
//   y1g[n]  = bf16(relu(s1[n] @ W1 + b1) * dinv[n])         (2 planes x 16bf, 3.2MB each)
//   s2[c]   = dinv[c] * (sum_{r->c} y1g[r] + y1g[c])        (per-plane CSR gather)
//   out[g]  = (sum_{batch==g} s2) @ W2 + cnt[g]*b2          (fused pool+GEMV)
//
// R4 lesson: the single-block k_gscan was a 60us serial stage (occupancy
// 0.15%). Replaced with a 2-kernel multi-block scan (~5us). CSR build keeps
// the partitioned counting sort (dense per-block stores, LDS-only atomics).

constexpr int BLK = 256;
constexpr int EPB = 8192;          // edges per block in hist/scatter
constexpr int BSH = 10;            // 1024 nodes per bucket
constexpr int BKTN = 1 << BSH;

__device__ inline unsigned short f2bf(float x) {
  unsigned u = __float_as_uint(x);
  u += 0x7FFF + ((u >> 16) & 1);   // round-to-nearest-even
  return (unsigned short)(u >> 16);
}
__device__ inline float bf2f(unsigned short h) {
  return __uint_as_float((unsigned)h << 16);
}

// per-block LDS histogram of col buckets
__global__ __launch_bounds__(BLK) void k_hist(const int* __restrict__ col, int E,
                                              int nbkt, int nblk,
                                              int* __restrict__ hist) {
  __shared__ int h[1024];
  int tid = threadIdx.x, blk = blockIdx.x;
  for (int i = tid; i < nbkt; i += BLK) h[i] = 0;
  __syncthreads();
  int e0 = blk * EPB, e1 = min(E, e0 + EPB);
  for (int e = e0 + tid; e < e1; e += BLK) atomicAdd(&h[col[e] >> BSH], 1);
  __syncthreads();
  for (int b = tid; b < nbkt; b += BLK) hist[b * nblk + blk] = h[b];
}

// multi-block scan, stage 1: block-local exclusive scan + block sums
__global__ __launch_bounds__(1024) void k_scan_a(const int* __restrict__ hist, int tot,
                                                 int* __restrict__ off,
                                                 int* __restrict__ bsums) {
  __shared__ int sd[1024];
  int tid = threadIdx.x;
  int i = blockIdx.x * 1024 + tid;
  int v = (i < tot) ? hist[i] : 0;
  sd[tid] = v;
  __syncthreads();
  for (int o = 1; o < 1024; o <<= 1) {
    int u = (tid >= o) ? sd[tid - o] : 0;
    __syncthreads();
    sd[tid] += u;
    __syncthreads();
  }
  if (i < tot) off[i] = sd[tid] - v;  // block-local exclusive
  if (tid == 1023) bsums[blockIdx.x] = sd[tid];
}

// stage 2: add prefix of block sums (recomputed per block, <=64 adds);
// derive bucket segment starts
__global__ __launch_bounds__(1024) void k_scan_c(int tot, int nblk, int nbkt, int E,
                                                 const int* __restrict__ bsums,
                                                 int* __restrict__ off,
                                                 int* __restrict__ bucket_off) {
  __shared__ int sbase;
  int tid = threadIdx.x, b = blockIdx.x;
  if (tid == 0) {
    int s = 0;
    for (int j = 0; j < b; ++j) s += bsums[j];
    sbase = s;
  }
  __syncthreads();
  int i = b * 1024 + tid;
  if (i < tot) {
    int v = off[i] + sbase;
    off[i] = v;
    if (i % nblk == 0) bucket_off[i / nblk] = v;
  }
  if (i == 0) bucket_off[nbkt] = E;
}

// scatter packed edges into bucket-major segments; all stores dense per block
__global__ __launch_bounds__(BLK) void k_scatter(const int* __restrict__ row,
                                                 const int* __restrict__ col, int E,
                                                 int nbkt, int nblk,
                                                 const int* __restrict__ off,
                                                 int* __restrict__ staging) {
  __shared__ int base[1024];
  __shared__ int cur[1024];
  int tid = threadIdx.x, blk = blockIdx.x;
  for (int b = tid; b < nbkt; b += BLK) {
    base[b] = off[b * nblk + blk];
    cur[b] = 0;
  }
  __syncthreads();
  int e0 = blk * EPB, e1 = min(E, e0 + EPB);
  for (int e = e0 + tid; e < e1; e += BLK) {
    int c = col[e];
    int b = c >> BSH;
    int rk = atomicAdd(&cur[b], 1);
    staging[base[b] + rk] = (row[e] << BSH) | (c & (BKTN - 1));
  }
}

// per-bucket (1024 nodes): LDS count -> scan -> col_ptr/dinv -> edge_row fill
__global__ __launch_bounds__(1024) void k_build(const int* __restrict__ staging,
                                                const int* __restrict__ bucket_off,
                                                int N, int E,
                                                int* __restrict__ col_ptr,
                                                float* __restrict__ dinv,
                                                int* __restrict__ edge_row) {
  __shared__ int cnt[BKTN];
  __shared__ int sc[BKTN];
  __shared__ int lcur[BKTN];
  int tid = threadIdx.x, b = blockIdx.x;
  int beg = bucket_off[b], end = bucket_off[b + 1];
  cnt[tid] = 0;
  __syncthreads();
  for (int i = beg + tid; i < end; i += 1024)
    atomicAdd(&cnt[staging[i] & (BKTN - 1)], 1);
  __syncthreads();
  int c = cnt[tid];
  sc[tid] = c;
  __syncthreads();
  for (int o = 1; o < BKTN; o <<= 1) {
    int v = (tid >= o) ? sc[tid - o] : 0;
    __syncthreads();
    sc[tid] += v;
    __syncthreads();
  }
  int node = (b << BSH) + tid;
  if (node < N) {
    int pos = beg + sc[tid] - c;
    col_ptr[node] = pos;
    lcur[tid] = pos;
    dinv[node] = rsqrtf((float)(c + 1));  // +1 self-loop
  }
  if (b == 0 && tid == 0) col_ptr[N] = E;
  __syncthreads();
  for (int i = beg + tid; i < end; i += 1024) {
    int p = staging[i];
    int pos = atomicAdd(&lcur[p & (BKTN - 1)], 1);
    edge_row[pos] = p >> BSH;
  }
}

// ag1[n] = bf16(emb[x_ids[n]] * dinv[n]); 2 lanes/node x 8 feats
__global__ __launch_bounds__(BLK) void k_prep(const int* __restrict__ x_ids,
                                              const float* __restrict__ emb,
                                              const float* __restrict__ dinv, int N,
                                              unsigned short* __restrict__ ag1) {
  int t = blockIdx.x * BLK + threadIdx.x;
  int n = t >> 1, half = t & 1;
  if (n >= N) return;
  float d = dinv[n];
  const float* er = emb + (size_t)x_ids[n] * 16 + half * 8;
  float4 a = *(const float4*)(er);
  float4 b = *(const float4*)(er + 4);
  uint4 o;
  o.x = (unsigned)f2bf(a.x * d) | ((unsigned)f2bf(a.y * d) << 16);
  o.y = (unsigned)f2bf(a.z * d) | ((unsigned)f2bf(a.w * d) << 16);
  o.z = (unsigned)f2bf(b.x * d) | ((unsigned)f2bf(b.y * d) << 16);
  o.w = (unsigned)f2bf(b.z * d) | ((unsigned)f2bf(b.w * d) << 16);
  *(uint4*)(ag1 + (size_t)n * 16 + half * 8) = o;
}

// s1[c] = dinv[c] * (sum ag1[r] + ag1[c]); 4 lanes/node x 4 feats (bf16 in)
__global__ __launch_bounds__(BLK) void k_agg1(const unsigned short* __restrict__ ag1,
                                              const int* __restrict__ col_ptr,
                                              const int* __restrict__ edge_row,
                                              const float* __restrict__ dinv, int N,
                                              float* __restrict__ s1) {
  int t = blockIdx.x * BLK + threadIdx.x;
  int n = t >> 2, ch = t & 3;
  if (n >= N) return;
  int off = ch * 4;
  uint2 sv = *(const uint2*)(ag1 + (size_t)n * 16 + off);
  float a0 = bf2f(sv.x & 0xFFFF), a1 = bf2f(sv.x >> 16);
  float a2 = bf2f(sv.y & 0xFFFF), a3 = bf2f(sv.y >> 16);
  int beg = col_ptr[n], end = col_ptr[n + 1];
  for (int i = beg; i < end; ++i) {
    int r = edge_row[i];
    uint2 v = *(const uint2*)(ag1 + (size_t)r * 16 + off);
    a0 += bf2f(v.x & 0xFFFF); a1 += bf2f(v.x >> 16);
    a2 += bf2f(v.y & 0xFFFF); a3 += bf2f(v.y >> 16);
  }
  float d = dinv[n];
  float4 o = {a0 * d, a1 * d, a2 * d, a3 * d};
  *(float4*)(s1 + (size_t)n * 16 + off) = o;
}

// y1g[n] = bf16(relu(s1[n] @ W1 + b1) * dinv[n]); written as 2 planes x 16bf
__global__ __launch_bounds__(BLK) void k_t1(const float* __restrict__ s1,
                                            const float* __restrict__ W1,
                                            const float* __restrict__ b1,
                                            const float* __restrict__ dinv, int N,
                                            unsigned short* __restrict__ y1g) {
  __shared__ float W[16 * 32];
  __shared__ float bb[32];
  int tid = threadIdx.x;
  for (int i = tid; i < 512; i += BLK) W[i] = W1[i];
  if (tid < 32) bb[tid] = b1[tid];
  __syncthreads();
  int t = blockIdx.x * BLK + tid;
  int n = t >> 3, ch = t & 7;
  if (n >= N) return;
  const float* sr = s1 + (size_t)n * 16;
  float x[16];
#pragma unroll
  for (int k = 0; k < 16; ++k) x[k] = sr[k];
  int f0 = ch * 4;
  float a0 = bb[f0], a1 = bb[f0 + 1], a2 = bb[f0 + 2], a3 = bb[f0 + 3];
#pragma unroll
  for (int k = 0; k < 16; ++k) {
    float xv = x[k];
    const float* wr = &W[k * 32 + f0];
    a0 += xv * wr[0]; a1 += xv * wr[1]; a2 += xv * wr[2]; a3 += xv * wr[3];
  }
  float d = dinv[n];
  a0 = fmaxf(a0, 0.f) * d;
  a1 = fmaxf(a1, 0.f) * d;
  a2 = fmaxf(a2, 0.f) * d;
  a3 = fmaxf(a3, 0.f) * d;
  int plane = ch >> 2, col0 = f0 & 15;
  uint2 o;
  o.x = (unsigned)f2bf(a0) | ((unsigned)f2bf(a1) << 16);
  o.y = (unsigned)f2bf(a2) | ((unsigned)f2bf(a3) << 16);
  *(uint2*)(y1g + (size_t)plane * N * 16 + (size_t)n * 16 + col0) = o;
}

// per-plane: s2p[c] = dinv[c]*(sum y1p[r] + y1p[c]); 4 lanes/node x 4 feats
__global__ __launch_bounds__(BLK) void k_agg2(const unsigned short* __restrict__ y1p,
                                              const int* __restrict__ col_ptr,
                                              const int* __restrict__ edge_row,
                                              const float* __restrict__ dinv, int N,
                                              float* __restrict__ s2p) {
  int t = blockIdx.x * BLK + threadIdx.x;
  int n = t >> 2, ch = t & 3;
  if (n >= N) return;
  int off = ch * 4;
  uint2 sv = *(const uint2*)(y1p + (size_t)n * 16 + off);
  float a0 = bf2f(sv.x & 0xFFFF), a1 = bf2f(sv.x >> 16);
  float a2 = bf2f(sv.y & 0xFFFF), a3 = bf2f(sv.y >> 16);
  int beg = col_ptr[n], end = col_ptr[n + 1];
  for (int i = beg; i < end; ++i) {
    int r = edge_row[i];
    uint2 v = *(const uint2*)(y1p + (size_t)r * 16 + off);
    a0 += bf2f(v.x & 0xFFFF); a1 += bf2f(v.x >> 16);
    a2 += bf2f(v.y & 0xFFFF); a3 += bf2f(v.y >> 16);
  }
  float d = dinv[n];
  float4 o = {a0 * d, a1 * d, a2 * d, a3 * d};
  *(float4*)(s2p + (size_t)n * 16 + off) = o;
}

// batch is SORTED: block g binary-searches its node range, sums s2 rows
// (plane-major layout), then out[g] = psum @ W2 + cnt*b2. No atomics.
__global__ __launch_bounds__(BLK) void k_pool(const float* __restrict__ s2,
                                              const int* __restrict__ batch, int N,
                                              const float* __restrict__ W2,
                                              const float* __restrict__ b2,
                                              float* __restrict__ out) {
  __shared__ int se[2];
  __shared__ float sd[BLK];
  int g = blockIdx.x, tid = threadIdx.x;
  if (tid < 2) {
    int v = g + tid;
    int lo = 0, hi = N;
    while (lo < hi) {
      int mid = (lo + hi) >> 1;
      if (batch[mid] < v) lo = mid + 1; else hi = mid;
    }
    se[tid] = lo;
  }
  __syncthreads();
  int start = se[0], end = se[1];
  int f = tid & 31, grp = tid >> 5;
  const float* base = s2 + (size_t)(f >> 4) * N * 16 + (f & 15);
  float acc = 0.f;
  for (int n = start + grp; n < end; n += 8) acc += base[(size_t)n * 16];
  sd[tid] = acc;
  __syncthreads();
  if (tid < 128) sd[tid] += sd[tid + 128];
  __syncthreads();
  if (tid < 64) sd[tid] += sd[tid + 64];
  __syncthreads();
  if (tid < 32) sd[tid] += sd[tid + 32];
  __syncthreads();
  if (tid < 41) {
    float o = (float)(end - start) * b2[tid];
#pragma unroll
    for (int k = 0; k < 32; ++k) o += sd[k] * W2[k * 41 + tid];
    out[(size_t)g * 41 + tid] = o;
  }
}

extern "C" void kernel_launch(void* const* d_in, const int* in_sizes, int n_in,
                              void* d_out, int out_size, void* d_ws, size_t ws_size,
                              hipStream_t stream) {
  const int* x_ids = (const int*)d_in[0];
  const int* edge_index = (const int*)d_in[1];
  const int* batch = (const int*)d_in[2];
  const float* emb = (const float*)d_in[3];
  const float* W1 = (const float*)d_in[4];
  const float* b1 = (const float*)d_in[5];
  const float* W2 = (const float*)d_in[6];
  const float* b2 = (const float*)d_in[7];
  float* out = (float*)d_out;

  const int N = in_sizes[0];
  const int E = in_sizes[1] / 2;
  const int G = out_size / 41;
  const int* row = edge_index;
  const int* col = edge_index + E;

  const int nbkt = (N + BKTN - 1) >> BSH;       // 98
  const int nblk = (E + EPB - 1) / EPB;         // 391
  const int tot = nbkt * nblk;                  // 38318
  const int nscan = (tot + 1023) >> 10;         // 38

  char* ws = (char*)d_ws;
  size_t woff = 0;
  auto alloc = [&](size_t bytes) -> char* {
    char* p = ws + woff;
    woff += (bytes + 255) & ~(size_t)255;
    return p;
  };
  size_t stage_bytes = (size_t)E * 4;
  size_t s2_bytes = (size_t)N * 32 * 4;
  int* staging = (int*)alloc(stage_bytes > s2_bytes ? stage_bytes : s2_bytes);
  int* edge_row = (int*)alloc((size_t)E * 4);
  int* col_ptr = (int*)alloc(((size_t)N + 1) * 4);
  float* dinv = (float*)alloc((size_t)N * 4);
  unsigned short* ag1 = (unsigned short*)alloc((size_t)N * 16 * 2);
  float* s1 = (float*)alloc((size_t)N * 16 * 4);
  unsigned short* y1g = (unsigned short*)alloc((size_t)N * 32 * 2);
  int* hist = (int*)alloc((size_t)tot * 4);
  int* off = (int*)alloc((size_t)tot * 4);
  int* bucket_off = (int*)alloc(((size_t)nbkt + 1) * 4);
  int* bsums = (int*)alloc((size_t)nscan * 4);
  float* s2 = (float*)staging;  // staging dead after k_build
  (void)ws_size; (void)n_in;

  k_hist<<<nblk, BLK, 0, stream>>>(col, E, nbkt, nblk, hist);
  k_scan_a<<<nscan, 1024, 0, stream>>>(hist, tot, off, bsums);
  k_scan_c<<<nscan, 1024, 0, stream>>>(tot, nblk, nbkt, E, bsums, off, bucket_off);
  k_scatter<<<nblk, BLK, 0, stream>>>(row, col, E, nbkt, nblk, off, staging);
  k_build<<<nbkt, 1024, 0, stream>>>(staging, bucket_off, N, E, col_ptr, dinv, edge_row);
  k_prep<<<(N * 2 + BLK - 1) / BLK, BLK, 0, stream>>>(x_ids, emb, dinv, N, ag1);
  k_agg1<<<(N * 4 + BLK - 1) / BLK, BLK, 0, stream>>>(ag1, col_ptr, edge_row, dinv, N, s1);
  k_t1<<<(N * 8 + BLK - 1) / BLK, BLK, 0, stream>>>(s1, W1, b1, dinv, N, y1g);
  k_agg2<<<(N * 4 + BLK - 1) / BLK, BLK, 0, stream>>>(y1g, col_ptr, edge_row, dinv, N, s2);
  k_agg2<<<(N * 4 + BLK - 1) / BLK, BLK, 0, stream>>>(y1g + (size_t)N * 16, col_ptr,
                                                      edge_row, dinv, N, s2 + (size_t)N * 16);
  k_pool<<<G, BLK, 0, stream>>>(s2, batch, N, W2, b2, out);
}